// Round 1
// baseline (193.795 us; speedup 1.0000x reference)
//
#include <hip/hip_runtime.h>
#include <stdint.h>

#define LOG2_HASHMAP_SIZE 19
#define HASHTABLE_MASK ((1u << LOG2_HASHMAP_SIZE) - 1u)
#define RES_F 128.0f

// 4 points per thread:
//   x is (N,3) f32 row-major -> 3 float4 loads = 12 floats = xyz of 4 points.
//   out is (N,2) f32 row-major -> 2 float4 stores = 8 floats = 4 points.
// Table gathers (8 float2 per point, 32 per thread) are independent -> MLP
// hides L2-hit latency (table is 4 MiB, fits per-XCD L2).
__global__ __launch_bounds__(256) void featurefield_kernel(
    const float4* __restrict__ x4,     // N/4 * 3 float4
    const float2* __restrict__ table,  // 2^19 float2
    float4* __restrict__ out4,         // N/4 * 2 float4
    int n_quads)
{
    int t = blockIdx.x * blockDim.x + threadIdx.x;
    if (t >= n_quads) return;

    float4 a = x4[3 * t + 0];
    float4 b = x4[3 * t + 1];
    float4 c = x4[3 * t + 2];

    float px[4] = {a.x, a.w, b.z, c.y};
    float py[4] = {a.y, b.x, b.w, c.z};
    float pz[4] = {a.z, b.y, c.x, c.w};

    uint32_t h[4][8];
    float dxs[4], dys[4], dzs[4];

    // Phase 1: compute all 32 hash indices (keeps gathers batched below).
    #pragma unroll
    for (int k = 0; k < 4; ++k) {
        float xs = px[k] * RES_F;
        float ys = py[k] * RES_F;
        float zs = pz[k] * RES_F;
        float fxf = floorf(xs), fyf = floorf(ys), fzf = floorf(zs);
        int fx = (int)fxf, fy = (int)fyf, fz = (int)fzf;
        int cx = (int)ceilf(xs), cy = (int)ceilf(ys), cz = (int)ceilf(zs);
        dxs[k] = xs - fxf;
        dys[k] = ys - fyf;
        dzs[k] = zs - fzf;

        uint32_t ufx = (uint32_t)fx, ucx = (uint32_t)cx;
        uint32_t fyp = (uint32_t)fy * 2654435761u;
        uint32_t cyp = (uint32_t)cy * 2654435761u;
        uint32_t fzp = (uint32_t)fz * 805459861u;
        uint32_t czp = (uint32_t)cz * 805459861u;

        h[k][0] = (ufx ^ fyp ^ fzp) & HASHTABLE_MASK;  // 000
        h[k][1] = (ucx ^ fyp ^ fzp) & HASHTABLE_MASK;  // 100
        h[k][2] = (ufx ^ cyp ^ fzp) & HASHTABLE_MASK;  // 010
        h[k][3] = (ufx ^ fyp ^ czp) & HASHTABLE_MASK;  // 001
        h[k][4] = (ucx ^ cyp ^ fzp) & HASHTABLE_MASK;  // 110
        h[k][5] = (ucx ^ fyp ^ czp) & HASHTABLE_MASK;  // 101
        h[k][6] = (ufx ^ cyp ^ czp) & HASHTABLE_MASK;  // 011
        h[k][7] = (ucx ^ cyp ^ czp) & HASHTABLE_MASK;  // 111
    }

    // Phase 2: issue all 32 gathers back-to-back (max loads in flight).
    float2 v[4][8];
    #pragma unroll
    for (int k = 0; k < 4; ++k) {
        #pragma unroll
        for (int j = 0; j < 8; ++j) {
            v[k][j] = table[h[k][j]];
        }
    }

    // Phase 3: trilinear interpolation, exactly per reference ordering.
    float2 res[4];
    #pragma unroll
    for (int k = 0; k < 4; ++k) {
        float dx = dxs[k], dy = dys[k], dz = dzs[k];
        float wx = 1.0f - dx, wy = 1.0f - dy, wz = 1.0f - dz;

        float c00x = v[k][0].x * wx + v[k][1].x * dx;
        float c00y = v[k][0].y * wx + v[k][1].y * dx;
        float c01x = v[k][3].x * wx + v[k][5].x * dx;
        float c01y = v[k][3].y * wx + v[k][5].y * dx;
        float c10x = v[k][2].x * wx + v[k][4].x * dx;
        float c10y = v[k][2].y * wx + v[k][4].y * dx;
        float c11x = v[k][6].x * wx + v[k][7].x * dx;
        float c11y = v[k][6].y * wx + v[k][7].y * dx;

        float c0x = c00x * wy + c10x * dy;
        float c0y = c00y * wy + c10y * dy;
        float c1x = c01x * wy + c11x * dy;
        float c1y = c01y * wy + c11y * dy;

        res[k].x = c0x * wz + c1x * dz;
        res[k].y = c0y * wz + c1y * dz;
    }

    out4[2 * t + 0] = make_float4(res[0].x, res[0].y, res[1].x, res[1].y);
    out4[2 * t + 1] = make_float4(res[2].x, res[2].y, res[3].x, res[3].y);
}

extern "C" void kernel_launch(void* const* d_in, const int* in_sizes, int n_in,
                              void* d_out, int out_size, void* d_ws, size_t ws_size,
                              hipStream_t stream) {
    const float4* x4 = (const float4*)d_in[0];
    const float2* table = (const float2*)d_in[1];
    float4* out4 = (float4*)d_out;

    int n_points = in_sizes[0] / 3;   // 4194304
    int n_quads = n_points / 4;       // 1048576

    int block = 256;
    int grid = (n_quads + block - 1) / block;  // 4096
    featurefield_kernel<<<grid, block, 0, stream>>>(x4, table, out4, n_quads);
}